// Round 5
// baseline (240.493 us; speedup 1.0000x reference)
//
#include <hip/hip_runtime.h>

#define L_SEQ 4096

typedef unsigned short u16;
typedef __bf16 bf16_t;
typedef bf16_t bf16x8 __attribute__((ext_vector_type(8)));
typedef float f32x4 __attribute__((ext_vector_type(4)));
typedef unsigned short u16x8 __attribute__((ext_vector_type(8)));
typedef unsigned short u16x4 __attribute__((ext_vector_type(4)));

__device__ __forceinline__ u16 f2b(float f) {
  unsigned u = __float_as_uint(f);
  u += 0x7fffu + ((u >> 16) & 1u);   // RNE
  return (u16)(u >> 16);
}
__device__ __forceinline__ float b2f(u16 b) {
  return __uint_as_float(((unsigned)b) << 16);
}

#define FENCE asm volatile("" ::: "memory")
#define BARRIER __builtin_amdgcn_s_barrier()
#define WAIT_LGKM0 asm volatile("s_waitcnt lgkmcnt(0)" ::: "memory")
#define WAIT_VM4 asm volatile("s_waitcnt vmcnt(4)" ::: "memory")
#define WAIT_VM6 asm volatile("s_waitcnt vmcnt(6)" ::: "memory")
#define WAIT_VM8 asm volatile("s_waitcnt vmcnt(8)" ::: "memory")
#define SB0 __builtin_amdgcn_sched_barrier(0)
#define AS1 __attribute__((address_space(1)))
#define AS3 __attribute__((address_space(3)))

// ---------------- fp32 [R][C] -> bf16 [C][R] transpose ----------------
__global__ __launch_bounds__(256) void k_transpose_cvt(const float* __restrict__ in,
                                                       u16* __restrict__ out,
                                                       int R, int C) {
  __shared__ float tile[32][33];
  int bx = blockIdx.x * 32, by = blockIdx.y * 32;
  int tx = threadIdx.x, ty = threadIdx.y;  // block (32,8)
#pragma unroll
  for (int i = 0; i < 32; i += 8)
    tile[ty + i][tx] = in[(size_t)(by + ty + i) * C + (bx + tx)];
  __syncthreads();
#pragma unroll
  for (int i = 0; i < 32; i += 8)
    out[(size_t)(bx + ty + i) * R + (by + tx)] = f2b(tile[tx][ty + i]);
}

// ---------------- persistent 256x256 8-phase bf16 GEMM ----------------
// A_F32: A is fp32 in global; reg-staged (load @P1/P2/P5/P6, cvt+ds_write
// @P3/P4/P7/P8 under counted vmcnt) -> fuses the bf16 conversion into GEMM1.
// Else: A bf16, global_load_lds staging (round-4 proven schedule).
template <bool OUT_BF16, bool A_F32>
__global__ __launch_bounds__(512, 2) void k_gemm256p(const void* __restrict__ Av,
                                                     const u16* __restrict__ Bt,
                                                     void* __restrict__ Cv,
                                                     int M, int N, int K,
                                                     int ntiles, int gx) {
  __shared__ __align__(16) char lds[131072];
  const u16* A16 = (const u16*)Av;
  const float* A32 = (const float*)Av;
  const int tid = threadIdx.x;
  const int wid = tid >> 6, lane = tid & 63;
  const int wm = wid >> 2, wn = wid & 3;      // 2x4 wave grid
  const int lr = lane & 15, lq = lane >> 4;
  const int xr = (lr & 7) << 4;               // read-side XOR swizzle
  const int koff0 = (lq * 16) ^ xr;
  const int koff1 = (64 | (lq * 16)) ^ xr;

  const int cpx = 32 * ntiles;                // (256*ntiles)/8
  auto tilecoord = [&](int ff, int& mm, int& nn) {
    int swz = (ff & 7) * cpx + (ff >> 3);
    mm = (swz / gx) * 256; nn = (swz % gx) * 256;
  };

  // per-thread staging constants (elements; source pre-swizzled to match reads)
  const int rowT = tid >> 3;                                        // 0..63
  const int colT = (((tid * 16) & 127) ^ ((rowT & 7) << 4)) >> 1;   // elem units
  const size_t r64K = (size_t)64 * K;
  const size_t r128K = (size_t)128 * K;

  int m0, n0;
  tilecoord(blockIdx.x, m0, n0);
  const u16* pA16 = A16 + (size_t)(m0 + rowT) * K + colT;
  const float* pA32 = A32 + (size_t)(m0 + rowT) * K + colT;
  const u16* pBc = Bt + (size_t)(n0 + rowT) * K + colT;

  f32x4 acc[8][4];
  bf16x8 a[4][2];
  bf16x8 bb[2][2][2];
  f32x4 qA[2][4];   // in-flight fp32 A half-tiles (A_F32 path); static-indexed

  auto STGB = [&](const u16* bp, int region, size_t hoff, int k0) {
    const u16* s0 = bp + hoff + k0;
    __builtin_amdgcn_global_load_lds((const AS1 void*)s0,
                                     (AS3 void*)(lds + region + wid * 1024), 16, 0, 0);
    __builtin_amdgcn_global_load_lds((const AS1 void*)(s0 + r64K),
                                     (AS3 void*)(lds + region + 8192 + wid * 1024), 16, 0, 0);
  };
  auto LA = [&](int qi, const float* bp, size_t hoff, int k0) {
    const float* s0 = bp + hoff + k0;
    qA[qi][0] = *(const f32x4*)(s0);
    qA[qi][1] = *(const f32x4*)(s0 + 4);
    qA[qi][2] = *(const f32x4*)(s0 + r64K);
    qA[qi][3] = *(const f32x4*)(s0 + r64K + 4);
  };
  auto WA = [&](int qi, int region) {
    u16x8 o0, o1;
#pragma unroll
    for (int j = 0; j < 4; ++j) {
      o0[j] = f2b(qA[qi][0][j]); o0[4 + j] = f2b(qA[qi][1][j]);
      o1[j] = f2b(qA[qi][2][j]); o1[4 + j] = f2b(qA[qi][3][j]);
    }
    *(u16x8*)(lds + region + tid * 16) = o0;
    *(u16x8*)(lds + region + 8192 + tid * 16) = o1;
  };
  auto rdA = [&](int dbuf, int mh) {
#pragma unroll
    for (int mi = 0; mi < 4; ++mi) {
      const int base = dbuf * 65536 + wm * 16384 + (mh * 64 + mi * 16 + lr) * 128;
      a[mi][0] = *(const bf16x8*)(lds + base + koff0);
      a[mi][1] = *(const bf16x8*)(lds + base + koff1);
    }
  };
  auto rdB = [&](int dbuf, int nh, int bset) {
#pragma unroll
    for (int ni = 0; ni < 2; ++ni) {
      const int base = dbuf * 65536 + 32768 + (wn >> 1) * 16384 +
                       ((wn & 1) * 64 + nh * 32 + ni * 16 + lr) * 128;
      bb[bset][ni][0] = *(const bf16x8*)(lds + base + koff0);
      bb[bset][ni][1] = *(const bf16x8*)(lds + base + koff1);
    }
  };
  auto mfma16 = [&](int mh, int nh, int bset) {
    __builtin_amdgcn_s_setprio(1);
#pragma unroll
    for (int kk = 0; kk < 2; ++kk)           // kk OUTER: acc reuse 8 instrs apart
#pragma unroll
      for (int ni = 0; ni < 2; ++ni)
#pragma unroll
        for (int mi = 0; mi < 4; ++mi)
          acc[mh * 4 + mi][nh * 2 + ni] = __builtin_amdgcn_mfma_f32_16x16x32_bf16(
              a[mi][kk], bb[bset][ni][kk], acc[mh * 4 + mi][nh * 2 + ni], 0, 0, 0);
    __builtin_amdgcn_s_setprio(0);
  };

  // ---- prologue: buf0 complete; buf1.B in flight (4 outstanding) ----
  if constexpr (A_F32) {
    LA(0, pA32, 0, 0);
    LA(1, pA32, r128K, 0);
    STGB(pBc, 32768, 0, 0);
    STGB(pBc, 49152, r128K, 0);
    STGB(pBc, 65536 + 32768, 0, 64);
    STGB(pBc, 65536 + 49152, r128K, 64);
    WAIT_VM8;            // qA done
    WA(0, 0); WA(1, 16384);
    WAIT_VM4;            // buf0.B done; buf1.B (4) in flight
    WAIT_LGKM0; FENCE; BARRIER;
  } else {
    STGB(pA16, 0,             0,     0);
    STGB(pBc,  32768,         0,     0);
    STGB(pBc,  49152,         r128K, 0);
    STGB(pA16, 16384,         r128K, 0);
    STGB(pBc,  65536 + 32768, 0,     64);
    STGB(pBc,  65536 + 49152, r128K, 64);
    WAIT_VM4; FENCE; BARRIER;
  }

  const int NT = K >> 6;
  const int NI = NT >> 1;

  for (int tt = 0; tt < ntiles; ++tt) {
    const bool hasn = (tt + 1 < ntiles);
    int m0n = m0, n0n = n0;
    if (hasn) tilecoord(blockIdx.x + (tt + 1) * 256, m0n, n0n);
    const u16* pAn16 = hasn ? (A16 + (size_t)(m0n + rowT) * K + colT) : pA16;
    const float* pAn32 = hasn ? (A32 + (size_t)(m0n + rowT) * K + colT) : pA32;
    const u16* pBn = hasn ? (Bt + (size_t)(n0n + rowT) * K + colT) : pBc;

    {
      f32x4 z = {0.f, 0.f, 0.f, 0.f};
#pragma unroll
      for (int i = 0; i < 8; ++i)
#pragma unroll
        for (int j = 0; j < 4; ++j) acc[i][j] = z;
    }

    for (int it = 0; it < NI; ++it) {
      const int kP1 = (2 * it + 1) * 64;              // always < K
      const bool last = (it == NI - 1);
      const int kA = last ? 0 : (2 * it + 2) * 64;    // wrap -> next tile k=0
      const int kB = last ? 64 : (2 * it + 3) * 64;   // wrap -> next tile k=64
      const u16* sA16 = last ? pAn16 : pA16;
      const float* sA32 = last ? pAn32 : pA32;
      const u16* sB = last ? pBn : pBc;

      // P1: (mh0,nh0) buf0; A-stage buf1.A-h0 @ kP1
      rdA(0, 0); rdB(0, 0, 0);
      if constexpr (A_F32) LA(0, pA32, 0, kP1);
      else STGB(pA16, 65536, 0, kP1);
      FENCE; BARRIER; WAIT_LGKM0; SB0;
      mfma16(0, 0, 0);
      FENCE; BARRIER;
      // P2: (mh0,nh1); A-stage buf1.A-h1 @ kP1
      rdB(0, 1, 1);
      if constexpr (A_F32) LA(1, pA32, r128K, kP1);
      else STGB(pA16, 65536 + 16384, r128K, kP1);
      FENCE; BARRIER; WAIT_LGKM0; SB0;
      mfma16(0, 1, 1);
      FENCE; BARRIER;
      // P3: (mh1,nh1); stage buf0.B-h0 @ kA; [A_F32: write buf1.A-h0]
      rdA(0, 1);
      STGB(sB, 32768, 0, kA);
      if constexpr (A_F32) { WAIT_VM6; WA(0, 65536); }
      FENCE; BARRIER; WAIT_LGKM0; SB0;
      mfma16(1, 1, 1);
      FENCE; BARRIER;
      // P4: (mh1,nh0); stage buf0.B-h1 @ kA; [A_F32: write buf1.A-h1]
      STGB(sB, 49152, r128K, kA);
      if constexpr (A_F32) { WAIT_VM4; WA(1, 65536 + 16384); }
      FENCE; BARRIER; WAIT_LGKM0; SB0;
      mfma16(1, 0, 0);
      if constexpr (!A_F32) WAIT_VM4;
      FENCE; BARRIER;
      // P5: (mh0,nh0) buf1; A-stage buf0.A-h0 @ kA
      rdA(1, 0); rdB(1, 0, 0);
      if constexpr (A_F32) LA(0, sA32, 0, kA);
      else STGB(sA16, 0, 0, kA);
      FENCE; BARRIER; WAIT_LGKM0; SB0;
      mfma16(0, 0, 0);
      FENCE; BARRIER;
      // P6: (mh0,nh1); A-stage buf0.A-h1 @ kA
      rdB(1, 1, 1);
      if constexpr (A_F32) LA(1, sA32, r128K, kA);
      else STGB(sA16, 16384, r128K, kA);
      FENCE; BARRIER; WAIT_LGKM0; SB0;
      mfma16(0, 1, 1);
      FENCE; BARRIER;
      // P7: (mh1,nh1); stage buf1.B-h0 @ kB; [A_F32: write buf0.A-h0]
      rdA(1, 1);
      STGB(sB, 65536 + 32768, 0, kB);
      if constexpr (A_F32) { WAIT_VM6; WA(0, 0); }
      FENCE; BARRIER; WAIT_LGKM0; SB0;
      mfma16(1, 1, 1);
      FENCE; BARRIER;
      // P8: (mh1,nh0); stage buf1.B-h1 @ kB; [A_F32: write buf0.A-h1]
      STGB(sB, 65536 + 49152, r128K, kB);
      if constexpr (A_F32) { WAIT_VM4; WA(1, 16384); }
      FENCE; BARRIER; WAIT_LGKM0; SB0;
      mfma16(1, 0, 0);
      if constexpr (!A_F32) WAIT_VM4;
      FENCE; BARRIER;
    }

    // ---- epilogue (current tile); stores overlap next tile's early phases ----
#pragma unroll
    for (int mi = 0; mi < 8; ++mi)
#pragma unroll
      for (int ni = 0; ni < 4; ++ni) {
        const int r0 = m0 + wm * 128 + (mi >> 2) * 64 + (mi & 3) * 16 + lq * 4;
        const int c = n0 + wn * 64 + (ni >> 1) * 32 + (ni & 1) * 16 + lr;
#pragma unroll
        for (int r = 0; r < 4; ++r) {
          const float v = acc[mi][ni][r];
          if (OUT_BF16)
            ((u16*)Cv)[(size_t)(r0 + r) * N + c] = f2b(v);
          else
            ((float*)Cv)[(size_t)(r0 + r) * N + c] = v;
        }
      }

    m0 = m0n; n0 = n0n; pA16 = pAn16; pA32 = pAn32; pBc = pBn;
  }
}

// ---------------- segment attention: MFMA + in-register softmax ----------------
__global__ __launch_bounds__(256) void k_attn2(const u16* __restrict__ qkv,
                                               const int* __restrict__ hmap,
                                               u16* __restrict__ att) {
  __shared__ u16 VT[64 * 40];       // V^T[d][k], stride 40 u16, XOR-chunk swizzled
  __shared__ u16 Pl[4][16 * 40];    // per-wave P[16 q][32 k], stride 40 u16

  const int blk = blockIdx.x;
  const int b = blk >> 10, h = (blk >> 6) & 15, s = blk & 63;
  const int t = threadIdx.x, w = t >> 6, lane = t & 63;
  const int lr = lane & 15, lq = lane >> 4;
  const int* hm = hmap + s * 64;
  const size_t bb = (size_t)b * L_SEQ;

  // ---- stage V^T (dilated rows; XOR-chunk swizzle kills write conflicts) ----
  {
    const int kj = t >> 3, d0 = (t & 7) * 8;
    const u16* p = qkv + (bb + hm[2 * kj]) * 3072 + 2048 + h * 64 + d0;
    u16x8 v = *(const u16x8*)p;
#pragma unroll
    for (int j = 0; j < 8; ++j) {
      const int d = d0 + j;
      const int chunk = (kj >> 3) ^ ((d >> 3) & 3);
      VT[d * 40 + chunk * 8 + (kj & 7)] = v[j];
    }
  }

  // ---- Q/K fragment gather: direct global, A/B-frag layouts ----
  const u16* qp = qkv + (bb + hm[16 * w + lr]) * 3072 + h * 64 + lq * 8;
  bf16x8 aq0 = *(const bf16x8*)(qp);
  bf16x8 aq1 = *(const bf16x8*)(qp + 32);
  bf16x8 bk[2][2];
#pragma unroll
  for (int nk = 0; nk < 2; ++nk) {
    const u16* kp = qkv + (bb + hm[2 * (nk * 16 + lr)]) * 3072 + 1024 + h * 64 + lq * 8;
    bk[nk][0] = *(const bf16x8*)(kp);
    bk[nk][1] = *(const bf16x8*)(kp + 32);
  }

  // ---- scores: S[q][kcol], kcol = lr + 16*nk ----
  f32x4 z4 = {0.f, 0.f, 0.f, 0.f};
  f32x4 s0 = __builtin_amdgcn_mfma_f32_16x16x32_bf16(aq0, bk[0][0], z4, 0, 0, 0);
  s0 = __builtin_amdgcn_mfma_f32_16x16x32_bf16(aq1, bk[0][1], s0, 0, 0, 0);
  f32x4 s1 = __builtin_amdgcn_mfma_f32_16x16x32_bf16(aq0, bk[1][0], z4, 0, 0, 0);
  s1 = __builtin_amdgcn_mfma_f32_16x16x32_bf16(aq1, bk[1][1], s1, 0, 0, 0);

  // ---- in-register softmax over 32 kcols (lr-group shuffle reduce) ----
  float inv[4];
  u16* Pw = Pl[w];
#pragma unroll
  for (int r = 0; r < 4; ++r) {
    float a0 = s0[r] * 0.125f, a1 = s1[r] * 0.125f;
    float m = fmaxf(a0, a1);
    m = fmaxf(m, __shfl_xor(m, 1));
    m = fmaxf(m, __shfl_xor(m, 2));
    m = fmaxf(m, __shfl_xor(m, 4));
    m = fmaxf(m, __shfl_xor(m, 8));
    float e0 = __expf(a0 - m), e1 = __expf(a1 - m);
    float sum = e0 + e1;
    sum += __shfl_xor(sum, 1);
    sum += __shfl_xor(sum, 2);
    sum += __shfl_xor(sum, 4);
    sum += __shfl_xor(sum, 8);
    inv[r] = 1.f / sum;
    Pw[(lq * 4 + r) * 40 + lr] = f2b(e0);
    Pw[(lq * 4 + r) * 40 + 16 + lr] = f2b(e1);
  }

  __syncthreads();   // VT visible to all waves; own P writes drained

  // ---- PV: out[q][d] = sum_k P[q][k] * VT[d][k] ----
  bf16x8 ap = *(const bf16x8*)(Pw + lr * 40 + lq * 8);
  f32x4 o[4];
#pragma unroll
  for (int nd = 0; nd < 4; ++nd) {
    const int row = nd * 16 + lr;
    const int chunk = lq ^ ((row >> 3) & 3);
    bf16x8 bv = *(const bf16x8*)(VT + row * 40 + chunk * 8);
    o[nd] = __builtin_amdgcn_mfma_f32_16x16x32_bf16(ap, bv, z4, 0, 0, 0);
  }

  // ---- scatter back to original token order (fuses inverse perm) ----
#pragma unroll
  for (int r = 0; r < 4; ++r) {
    u16* dst = att + (bb + hm[16 * w + lq * 4 + r]) * 1024 + h * 64 + lr;
#pragma unroll
    for (int nd = 0; nd < 4; ++nd)
      dst[nd * 16] = f2b(o[nd][r] * inv[r]);
  }
}

extern "C" void kernel_launch(void* const* d_in, const int* in_sizes, int n_in,
                              void* d_out, int out_size, void* d_ws, size_t ws_size,
                              hipStream_t stream) {
  const float* x = (const float*)d_in[0];
  const float* w_qkv = (const float*)d_in[1];
  const float* w_proj = (const float*)d_in[2];
  const int* hmap = (const int*)d_in[3];
  float* out = (float*)d_out;

  char* ws = (char*)d_ws;
  u16* qkvb  = (u16*)(ws);                   // 16384*3072*2 = 100663296 B
  u16* att   = (u16*)(ws + 100663296ull);    // 16384*1024*2 = 33554432 B
  u16* wqkvT = (u16*)(ws + 134217728ull);    // 3072*1024*2  = 6291456 B
  u16* wprojT= (u16*)(ws + 140509184ull);    // 1024*1024*2  = 2097152 B -> total 142606336 B

  k_transpose_cvt<<<dim3(3072 / 32, 1024 / 32), dim3(32, 8), 0, stream>>>(w_qkv, wqkvT, 1024, 3072);
  k_transpose_cvt<<<dim3(1024 / 32, 1024 / 32), dim3(32, 8), 0, stream>>>(w_proj, wprojT, 1024, 1024);
  // qkv = bf16(x) @ w_qkv (cvt fused into A-staging): 256 blocks x 3 tiles
  k_gemm256p<true, true><<<256, 512, 0, stream>>>(x, wqkvT, qkvb, 16384, 3072, 1024, 3, 12);
  k_attn2<<<4096, 256, 0, stream>>>(qkvb, hmap, att);
  // out = att @ w_proj (fp32 out): 256 blocks x 1 tile
  k_gemm256p<false, false><<<256, 512, 0, stream>>>(att, wprojT, out, 16384, 1024, 1024, 1, 4);
}

// Round 6
// 193.772 us; speedup vs baseline: 1.2411x; 1.2411x over previous
//
#include <hip/hip_runtime.h>

#define L_SEQ 4096

typedef unsigned short u16;
typedef __bf16 bf16_t;
typedef bf16_t bf16x8 __attribute__((ext_vector_type(8)));
typedef float f32x4 __attribute__((ext_vector_type(4)));
typedef unsigned short u16x8 __attribute__((ext_vector_type(8)));
typedef unsigned short u16x4 __attribute__((ext_vector_type(4)));

__device__ __forceinline__ u16 f2b(float f) {
  unsigned u = __float_as_uint(f);
  u += 0x7fffu + ((u >> 16) & 1u);   // RNE
  return (u16)(u >> 16);
}
__device__ __forceinline__ float b2f(u16 b) {
  return __uint_as_float(((unsigned)b) << 16);
}

#define FENCE asm volatile("" ::: "memory")
#define BARRIER __builtin_amdgcn_s_barrier()
#define WAIT_LGKM0 asm volatile("s_waitcnt lgkmcnt(0)" ::: "memory")
#define WAIT_VM4 asm volatile("s_waitcnt vmcnt(4)" ::: "memory")
#define SB0 __builtin_amdgcn_sched_barrier(0)
#define AS1 __attribute__((address_space(1)))
#define AS3 __attribute__((address_space(3)))

// ---------------- fp32 -> bf16 convert (BW-tuned: 64B load / 32B store per lane) ----
__global__ __launch_bounds__(256) void k_cvt(const float* __restrict__ in,
                                             u16* __restrict__ out, int n) {
  const int stride = gridDim.x * blockDim.x * 16;
  for (int i = (blockIdx.x * blockDim.x + threadIdx.x) * 16; i < n; i += stride) {
    f32x4 v0 = *reinterpret_cast<const f32x4*>(in + i);
    f32x4 v1 = *reinterpret_cast<const f32x4*>(in + i + 4);
    f32x4 v2 = *reinterpret_cast<const f32x4*>(in + i + 8);
    f32x4 v3 = *reinterpret_cast<const f32x4*>(in + i + 12);
    u16x8 o0, o1;
#pragma unroll
    for (int j = 0; j < 4; ++j) {
      o0[j] = f2b(v0[j]); o0[4 + j] = f2b(v1[j]);
      o1[j] = f2b(v2[j]); o1[4 + j] = f2b(v3[j]);
    }
    *reinterpret_cast<u16x8*>(out + i) = o0;
    *reinterpret_cast<u16x8*>(out + i + 8) = o1;
  }
}

// ---------------- fp32 [R][C] -> bf16 [C][R] transpose ----------------
__global__ __launch_bounds__(256) void k_transpose_cvt(const float* __restrict__ in,
                                                       u16* __restrict__ out,
                                                       int R, int C) {
  __shared__ float tile[32][33];
  int bx = blockIdx.x * 32, by = blockIdx.y * 32;
  int tx = threadIdx.x, ty = threadIdx.y;  // block (32,8)
#pragma unroll
  for (int i = 0; i < 32; i += 8)
    tile[ty + i][tx] = in[(size_t)(by + ty + i) * C + (bx + tx)];
  __syncthreads();
#pragma unroll
  for (int i = 0; i < 32; i += 8)
    out[(size_t)(bx + ty + i) * R + (by + tx)] = f2b(tile[tx][ty + i]);
}

// ---------------- persistent 256x256 8-phase bf16 GEMM (round-4 schedule) ----------
// grid = 256 blocks x ntiles. Tail "wrap" stages pre-stage the next tile, so the
// epilogue store-drain overlaps the next tile's P1-P3. kk-outermost MFMA order.
template <bool OUT_BF16>
__global__ __launch_bounds__(512, 2) void k_gemm256p(const u16* __restrict__ A,
                                                     const u16* __restrict__ Bt,
                                                     void* __restrict__ Cv,
                                                     int M, int N, int K,
                                                     int ntiles, int gx) {
  __shared__ __align__(16) char lds[131072];
  const int tid = threadIdx.x;
  const int wid = tid >> 6, lane = tid & 63;
  const int wm = wid >> 2, wn = wid & 3;      // 2x4 wave grid
  const int lr = lane & 15, lq = lane >> 4;
  const int xr = (lr & 7) << 4;               // read-side XOR swizzle
  const int koff0 = (lq * 16) ^ xr;
  const int koff1 = (64 | (lq * 16)) ^ xr;

  const int cpx = 32 * ntiles;                // (256*ntiles)/8
  auto tilecoord = [&](int ff, int& mm, int& nn) {
    int swz = (ff & 7) * cpx + (ff >> 3);
    mm = (swz / gx) * 256; nn = (swz % gx) * 256;
  };

  // per-thread staging constants (source pre-swizzled to match swizzled reads)
  const int rowT = tid >> 3;                                        // 0..63
  const int colT = (((tid * 16) & 127) ^ ((rowT & 7) << 4)) >> 1;   // u16 units
  const size_t r64K = (size_t)64 * K;
  const size_t r128K = (size_t)128 * K;

  int m0, n0;
  tilecoord(blockIdx.x, m0, n0);
  const u16* pAc = A + (size_t)(m0 + rowT) * K + colT;
  const u16* pBc = Bt + (size_t)(n0 + rowT) * K + colT;

  f32x4 acc[8][4];
  bf16x8 a[4][2];
  bf16x8 bb[2][2][2];

  auto STG = [&](const u16* bp, int region, size_t hoff, int k0) {
    const u16* s0 = bp + hoff + k0;
    __builtin_amdgcn_global_load_lds((const AS1 void*)s0,
                                     (AS3 void*)(lds + region + wid * 1024), 16, 0, 0);
    __builtin_amdgcn_global_load_lds((const AS1 void*)(s0 + r64K),
                                     (AS3 void*)(lds + region + 8192 + wid * 1024), 16, 0, 0);
  };
  auto rdA = [&](int dbuf, int mh) {
#pragma unroll
    for (int mi = 0; mi < 4; ++mi) {
      const int base = dbuf * 65536 + wm * 16384 + (mh * 64 + mi * 16 + lr) * 128;
      a[mi][0] = *(const bf16x8*)(lds + base + koff0);
      a[mi][1] = *(const bf16x8*)(lds + base + koff1);
    }
  };
  auto rdB = [&](int dbuf, int nh, int bset) {
#pragma unroll
    for (int ni = 0; ni < 2; ++ni) {
      const int base = dbuf * 65536 + 32768 + (wn >> 1) * 16384 +
                       ((wn & 1) * 64 + nh * 32 + ni * 16 + lr) * 128;
      bb[bset][ni][0] = *(const bf16x8*)(lds + base + koff0);
      bb[bset][ni][1] = *(const bf16x8*)(lds + base + koff1);
    }
  };
  auto mfma16 = [&](int mh, int nh, int bset) {
    __builtin_amdgcn_s_setprio(1);
#pragma unroll
    for (int kk = 0; kk < 2; ++kk)           // kk OUTER: acc reuse 8 instrs apart
#pragma unroll
      for (int ni = 0; ni < 2; ++ni)
#pragma unroll
        for (int mi = 0; mi < 4; ++mi)
          acc[mh * 4 + mi][nh * 2 + ni] = __builtin_amdgcn_mfma_f32_16x16x32_bf16(
              a[mi][kk], bb[bset][ni][kk], acc[mh * 4 + mi][nh * 2 + ni], 0, 0, 0);
    __builtin_amdgcn_s_setprio(0);
  };

  // ---- prologue: buf0 all 4 halves @ k=0; buf1.B halves @ k=64 ----
  STG(pAc, 0,             0,     0);
  STG(pBc, 32768,         0,     0);
  STG(pBc, 49152,         r128K, 0);
  STG(pAc, 16384,         r128K, 0);
  STG(pBc, 65536 + 32768, 0,     64);
  STG(pBc, 65536 + 49152, r128K, 64);
  WAIT_VM4; FENCE; BARRIER;

  const int NT = K >> 6;
  const int NI = NT >> 1;

  for (int tt = 0; tt < ntiles; ++tt) {
    const bool hasn = (tt + 1 < ntiles);
    int m0n = m0, n0n = n0;
    if (hasn) tilecoord(blockIdx.x + (tt + 1) * 256, m0n, n0n);
    const u16* pAn = hasn ? (A + (size_t)(m0n + rowT) * K + colT) : pAc;
    const u16* pBn = hasn ? (Bt + (size_t)(n0n + rowT) * K + colT) : pBc;

    {
      f32x4 z = {0.f, 0.f, 0.f, 0.f};
#pragma unroll
      for (int i = 0; i < 8; ++i)
#pragma unroll
        for (int j = 0; j < 4; ++j) acc[i][j] = z;
    }

    for (int it = 0; it < NI; ++it) {
      const int kP1 = (2 * it + 1) * 64;              // always < K
      const bool last = (it == NI - 1);
      const int kA = last ? 0 : (2 * it + 2) * 64;    // wrap -> next tile k=0
      const int kB = last ? 64 : (2 * it + 3) * 64;   // wrap -> next tile k=64
      const u16* sA = last ? pAn : pAc;
      const u16* sB = last ? pBn : pBc;

      // P1: (mh0,nh0) buf0; stage buf1.A-h0 @ kP1
      rdA(0, 0); rdB(0, 0, 0);
      STG(pAc, 65536, 0, kP1);
      FENCE; BARRIER; WAIT_LGKM0; SB0;
      mfma16(0, 0, 0);
      FENCE; BARRIER;
      // P2: (mh0,nh1); stage buf1.A-h1 @ kP1
      rdB(0, 1, 1);
      STG(pAc, 65536 + 16384, r128K, kP1);
      FENCE; BARRIER; WAIT_LGKM0; SB0;
      mfma16(0, 1, 1);
      FENCE; BARRIER;
      // P3: (mh1,nh1); stage buf0.B-h0 @ kA
      rdA(0, 1);
      STG(sB, 32768, 0, kA);
      FENCE; BARRIER; WAIT_LGKM0; SB0;
      mfma16(1, 1, 1);
      FENCE; BARRIER;
      // P4: (mh1,nh0) regs-only; stage buf0.B-h1 @ kA; vmcnt(4)
      STG(sB, 49152, r128K, kA);
      FENCE; BARRIER; WAIT_LGKM0; SB0;
      mfma16(1, 0, 0);
      WAIT_VM4; FENCE; BARRIER;
      // P5: (mh0,nh0) buf1; stage buf0.A-h0 @ kA
      rdA(1, 0); rdB(1, 0, 0);
      STG(sA, 0, 0, kA);
      FENCE; BARRIER; WAIT_LGKM0; SB0;
      mfma16(0, 0, 0);
      FENCE; BARRIER;
      // P6: (mh0,nh1); stage buf0.A-h1 @ kA
      rdB(1, 1, 1);
      STG(sA, 16384, r128K, kA);
      FENCE; BARRIER; WAIT_LGKM0; SB0;
      mfma16(0, 1, 1);
      FENCE; BARRIER;
      // P7: (mh1,nh1); stage buf1.B-h0 @ kB
      rdA(1, 1);
      STG(sB, 65536 + 32768, 0, kB);
      FENCE; BARRIER; WAIT_LGKM0; SB0;
      mfma16(1, 1, 1);
      FENCE; BARRIER;
      // P8: (mh1,nh0) regs-only; stage buf1.B-h1 @ kB; vmcnt(4)
      STG(sB, 65536 + 49152, r128K, kB);
      FENCE; BARRIER; WAIT_LGKM0; SB0;
      mfma16(1, 0, 0);
      WAIT_VM4; FENCE; BARRIER;
    }

    // ---- epilogue (current tile); stores overlap next tile's P1-P3 ----
#pragma unroll
    for (int mi = 0; mi < 8; ++mi)
#pragma unroll
      for (int ni = 0; ni < 4; ++ni) {
        const int r0 = m0 + wm * 128 + (mi >> 2) * 64 + (mi & 3) * 16 + lq * 4;
        const int c = n0 + wn * 64 + (ni >> 1) * 32 + (ni & 1) * 16 + lr;
#pragma unroll
        for (int r = 0; r < 4; ++r) {
          const float v = acc[mi][ni][r];
          if (OUT_BF16)
            ((u16*)Cv)[(size_t)(r0 + r) * N + c] = f2b(v);
          else
            ((float*)Cv)[(size_t)(r0 + r) * N + c] = v;
        }
      }

    m0 = m0n; n0 = n0n; pAc = pAn; pBc = pBn;
  }
}

// ---------------- segment attention: MFMA + in-register softmax ----------------
__global__ __launch_bounds__(256) void k_attn2(const u16* __restrict__ qkv,
                                               const int* __restrict__ hmap,
                                               u16* __restrict__ att) {
  __shared__ u16 VT[64 * 40];       // V^T[d][k], stride 40 u16, XOR-chunk swizzled
  __shared__ u16 Pl[4][16 * 40];    // per-wave P[16 q][32 k], stride 40 u16

  const int blk = blockIdx.x;
  const int b = blk >> 10, h = (blk >> 6) & 15, s = blk & 63;
  const int t = threadIdx.x, w = t >> 6, lane = t & 63;
  const int lr = lane & 15, lq = lane >> 4;
  const int* hm = hmap + s * 64;
  const size_t bb = (size_t)b * L_SEQ;

  // ---- stage V^T (dilated rows; XOR-chunk swizzle kills write conflicts) ----
  {
    const int kj = t >> 3, d0 = (t & 7) * 8;
    const u16* p = qkv + (bb + hm[2 * kj]) * 3072 + 2048 + h * 64 + d0;
    u16x8 v = *(const u16x8*)p;
#pragma unroll
    for (int j = 0; j < 8; ++j) {
      const int d = d0 + j;
      const int chunk = (kj >> 3) ^ ((d >> 3) & 3);
      VT[d * 40 + chunk * 8 + (kj & 7)] = v[j];
    }
  }

  // ---- Q/K fragment gather: direct global, A/B-frag layouts ----
  const u16* qp = qkv + (bb + hm[16 * w + lr]) * 3072 + h * 64 + lq * 8;
  bf16x8 aq0 = *(const bf16x8*)(qp);
  bf16x8 aq1 = *(const bf16x8*)(qp + 32);
  bf16x8 bk[2][2];
#pragma unroll
  for (int nk = 0; nk < 2; ++nk) {
    const u16* kp = qkv + (bb + hm[2 * (nk * 16 + lr)]) * 3072 + 1024 + h * 64 + lq * 8;
    bk[nk][0] = *(const bf16x8*)(kp);
    bk[nk][1] = *(const bf16x8*)(kp + 32);
  }

  // ---- scores: S[q][kcol], kcol = lr + 16*nk ----
  f32x4 z4 = {0.f, 0.f, 0.f, 0.f};
  f32x4 s0 = __builtin_amdgcn_mfma_f32_16x16x32_bf16(aq0, bk[0][0], z4, 0, 0, 0);
  s0 = __builtin_amdgcn_mfma_f32_16x16x32_bf16(aq1, bk[0][1], s0, 0, 0, 0);
  f32x4 s1 = __builtin_amdgcn_mfma_f32_16x16x32_bf16(aq0, bk[1][0], z4, 0, 0, 0);
  s1 = __builtin_amdgcn_mfma_f32_16x16x32_bf16(aq1, bk[1][1], s1, 0, 0, 0);

  // ---- in-register softmax over 32 kcols (lr-group shuffle reduce) ----
  float inv[4];
  u16* Pw = Pl[w];
#pragma unroll
  for (int r = 0; r < 4; ++r) {
    float a0 = s0[r] * 0.125f, a1 = s1[r] * 0.125f;
    float m = fmaxf(a0, a1);
    m = fmaxf(m, __shfl_xor(m, 1));
    m = fmaxf(m, __shfl_xor(m, 2));
    m = fmaxf(m, __shfl_xor(m, 4));
    m = fmaxf(m, __shfl_xor(m, 8));
    float e0 = __expf(a0 - m), e1 = __expf(a1 - m);
    float sum = e0 + e1;
    sum += __shfl_xor(sum, 1);
    sum += __shfl_xor(sum, 2);
    sum += __shfl_xor(sum, 4);
    sum += __shfl_xor(sum, 8);
    inv[r] = 1.f / sum;
    Pw[(lq * 4 + r) * 40 + lr] = f2b(e0);
    Pw[(lq * 4 + r) * 40 + 16 + lr] = f2b(e1);
  }

  __syncthreads();   // VT visible to all waves; own P writes drained

  // ---- PV: out[q][d] = sum_k P[q][k] * VT[d][k] ----
  bf16x8 ap = *(const bf16x8*)(Pw + lr * 40 + lq * 8);
  f32x4 o[4];
#pragma unroll
  for (int nd = 0; nd < 4; ++nd) {
    const int row = nd * 16 + lr;
    const int chunk = lq ^ ((row >> 3) & 3);
    bf16x8 bv = *(const bf16x8*)(VT + row * 40 + chunk * 8);
    o[nd] = __builtin_amdgcn_mfma_f32_16x16x32_bf16(ap, bv, z4, 0, 0, 0);
  }

  // ---- scatter back to original token order (fuses inverse perm) ----
#pragma unroll
  for (int r = 0; r < 4; ++r) {
    u16* dst = att + (bb + hm[16 * w + lq * 4 + r]) * 1024 + h * 64 + lr;
#pragma unroll
    for (int nd = 0; nd < 4; ++nd)
      dst[nd * 16] = f2b(o[nd][r] * inv[r]);
  }
}

extern "C" void kernel_launch(void* const* d_in, const int* in_sizes, int n_in,
                              void* d_out, int out_size, void* d_ws, size_t ws_size,
                              hipStream_t stream) {
  const float* x = (const float*)d_in[0];
  const float* w_qkv = (const float*)d_in[1];
  const float* w_proj = (const float*)d_in[2];
  const int* hmap = (const int*)d_in[3];
  float* out = (float*)d_out;

  char* ws = (char*)d_ws;
  u16* qkvb  = (u16*)(ws);                   // 16384*3072*2 = 100663296 B
  u16* xb    = (u16*)(ws + 100663296ull);    // 16384*1024*2 = 33554432 B
  u16* wqkvT = (u16*)(ws + 134217728ull);    // 3072*1024*2  = 6291456 B
  u16* wprojT= (u16*)(ws + 140509184ull);    // 1024*1024*2  = 2097152 B -> total 142606336 B
  u16* att = xb;  // xb dead after GEMM1

  k_cvt<<<4096, 256, 0, stream>>>(x, xb, 16384 * 1024);
  k_transpose_cvt<<<dim3(3072 / 32, 1024 / 32), dim3(32, 8), 0, stream>>>(w_qkv, wqkvT, 1024, 3072);
  k_transpose_cvt<<<dim3(1024 / 32, 1024 / 32), dim3(32, 8), 0, stream>>>(w_proj, wprojT, 1024, 1024);
  // qkv = xb @ w_qkv (bf16 out): 256 persistent blocks x 3 tiles (grid 12x64 tiles)
  k_gemm256p<true><<<256, 512, 0, stream>>>(xb, wqkvT, qkvb, 16384, 3072, 1024, 3, 12);
  k_attn2<<<4096, 256, 0, stream>>>(qkvb, hmap, att);
  // out = att @ w_proj (fp32 out): 256 blocks x 1 tile (grid 4x64 tiles)
  k_gemm256p<false><<<256, 512, 0, stream>>>(att, wprojT, out, 16384, 1024, 1024, 1, 4);
}